// Round 12
// baseline (273.262 us; speedup 1.0000x reference)
//
#include <hip/hip_runtime.h>
#include <stdint.h>

#define GM 4096   // 2*2048 rows of x
#define GN 8192   // out_features
#define GK 2048   // in_features

typedef float f32x4 __attribute__((ext_vector_type(4)));
typedef __bf16 bf16x8 __attribute__((ext_vector_type(8)));

__device__ __constant__ float NF4_LUT[16] = {
    -1.0f, -0.6961928009986877f, -0.5250730514526367f, -0.39491748809814453f,
    -0.28444138169288635f, -0.18477343022823334f, -0.09105003625154495f, 0.0f,
    0.07958029955625534f, 0.16093020141124725f, 0.24611230194568634f,
    0.33791524171829224f, 0.44070982933044434f, 0.5626170039176941f,
    0.7229568362236023f, 1.0f};

__device__ __forceinline__ unsigned short f32_to_bf16_rne(float f) {
  union { float f; uint32_t u; } v;
  v.f = f;
  uint32_t lsb = (v.u >> 16) & 1u;
  v.u += 0x7fffu + lsb;
  return (unsigned short)(v.u >> 16);
}

// ---- Pass 1 (merged): NF4 dequant -> bf16 W  AND  x fp32 -> bf16 ----
__global__ void __launch_bounds__(256) prep_kernel(
    const int* __restrict__ q, const float* __restrict__ scale,
    unsigned short* __restrict__ w, const float* __restrict__ x,
    unsigned short* __restrict__ xb) {
  int b = blockIdx.x;
  if (b < 8192) {
    __shared__ float lut[16];
    if (threadIdx.x < 16) lut[threadIdx.x] = NF4_LUT[threadIdx.x];
    __syncthreads();
    int t = b * 256 + threadIdx.x;
    const int4* q4 = reinterpret_cast<const int4*>(q);
    int4 c0 = q4[2 * t];
    int4 c1 = q4[2 * t + 1];
    float s = scale[t >> 3];
    int codes[8] = {c0.x, c0.y, c0.z, c0.w, c1.x, c1.y, c1.z, c1.w};
    union { unsigned short u[8]; int4 v; } r;
#pragma unroll
    for (int j = 0; j < 8; ++j)
      r.u[j] = f32_to_bf16_rne(lut[codes[j] & 15] * s);
    reinterpret_cast<int4*>(w)[t] = r.v;
  } else {
    int t = (b - 8192) * 256 + threadIdx.x;
    const float4* x4 = reinterpret_cast<const float4*>(x);
    float4 a = x4[2 * t];
    float4 bb = x4[2 * t + 1];
    union { unsigned short u[8]; int4 v; } r;
    r.u[0] = f32_to_bf16_rne(a.x);  r.u[1] = f32_to_bf16_rne(a.y);
    r.u[2] = f32_to_bf16_rne(a.z);  r.u[3] = f32_to_bf16_rne(a.w);
    r.u[4] = f32_to_bf16_rne(bb.x); r.u[5] = f32_to_bf16_rne(bb.y);
    r.u[6] = f32_to_bf16_rne(bb.z); r.u[7] = f32_to_bf16_rne(bb.w);
    reinterpret_cast<int4*>(xb)[t] = r.v;
  }
}

// ------ Pass 2: 256x128 tile, 4 waves, BK=32 dbuf, 2 BLOCKS/CU ------
// Cross-block overlap (m114): two independent 4-wave blocks co-resident per
// CU; while one drains vmcnt/barrier the other issues MFMA. No intra-block
// software pipeline (it cannot fit registers at 8 waves - R11 lesson).
// Per wave 128x64 out: acc 128 (AGPR) + frags 48 V ~= 210/wave; 2 waves/SIMD
// x 210 = 420 <= 512 pool -> no spill (R6's failure was launch_bounds(512,4)
// capping waves to 128 regs). LDS 48KB/block -> 2 blocks/CU by VGPR.
// Swizzle g ^ ((row>>1)&3): R6-verified 0 bank conflicts, refcheck'd.
#define AS1(p) ((const __attribute__((address_space(1))) void*)(p))
#define AS3(p) ((__attribute__((address_space(3))) void*)(p))

__global__ void __launch_bounds__(256, 1) gemm_cross_kernel(
    const unsigned short* __restrict__ A,  // [GM][GK] bf16 bits
    const unsigned short* __restrict__ B,  // [GN][GK] bf16 bits
    const float* __restrict__ bias, float* __restrict__ C) {
  constexpr int BK = 32, NT = GK / BK;  // 64 K-tiles
  __shared__ __align__(16) unsigned short As[2 * 256 * 32];  // 32 KB
  __shared__ __align__(16) unsigned short Bs[2 * 128 * 32];  // 16 KB

  int bid = blockIdx.x;                  // nwg = 1024, %8==0 -> bijective
  int swz = (bid & 7) * 128 + (bid >> 3);
  int bm = swz >> 6;                     // 0..15  (A panel, 2 per XCD)
  int bn = swz & 63;                     // 0..63
  int brow = bm * 256, bcol = bn * 128;

  int tid = threadIdx.x;                 // 256 threads = 4 waves
  int lane = tid & 63;
  int wave = tid >> 6;                   // 0..3
  int wr = wave >> 1;                    // 0..1 (M half: 128 rows)
  int wc = wave & 1;                     // 0..1 (N half: 64 cols)
  int fr = lane & 15;
  int slot = lane >> 4;

  const unsigned short* Abase = A + (size_t)brow * GK;
  const unsigned short* Bbase = B + (size_t)bcol * GK;

  f32x4 acc[8][4] = {};

  // stage 256x32 A tile (16KB: 1024 chunks, 4/thread) / 128x32 B (8KB, 2/thr)
  // linear LDS dest, inverse-swizzled global source (R6-verified pair).
  auto stageA = [&](int buf, int kt) {
#pragma unroll
    for (int i = 0; i < 4; ++i) {
      int c = tid + i * 256;
      int row = c >> 2;
      int gp = (c & 3) ^ ((row >> 1) & 3);
      __builtin_amdgcn_global_load_lds(
          AS1(Abase + (size_t)row * GK + kt + gp * 8),
          AS3((char*)As + buf * 16384 + c * 16), 16, 0, 0);
    }
  };
  auto stageB = [&](int buf, int kt) {
#pragma unroll
    for (int i = 0; i < 2; ++i) {
      int c = tid + i * 256;
      int row = c >> 2;
      int gp = (c & 3) ^ ((row >> 1) & 3);
      __builtin_amdgcn_global_load_lds(
          AS1(Bbase + (size_t)row * GK + kt + gp * 8),
          AS3((char*)Bs + buf * 8192 + c * 16), 16, 0, 0);
    }
  };
  auto ldA = [&](int buf, int row) -> bf16x8 {
    int off = buf * 16384 + row * 64 + ((slot ^ ((row >> 1) & 3)) << 4);
    return *reinterpret_cast<const bf16x8*>((const char*)As + off);
  };
  auto ldB = [&](int buf, int row) -> bf16x8 {
    int off = buf * 8192 + row * 64 + ((slot ^ ((row >> 1) & 3)) << 4);
    return *reinterpret_cast<const bf16x8*>((const char*)Bs + off);
  };

  stageA(0, 0);
  stageB(0, 0);
  __syncthreads();

#pragma unroll 1
  for (int t = 0; t < NT; ++t) {
    int buf = t & 1;
    if (t + 1 < NT) {
      stageA(buf ^ 1, (t + 1) * BK);
      stageB(buf ^ 1, (t + 1) * BK);
    }
    bf16x8 a[8], b[4];
#pragma unroll
    for (int m = 0; m < 8; ++m) a[m] = ldA(buf, wr * 128 + m * 16 + fr);
#pragma unroll
    for (int n = 0; n < 4; ++n) b[n] = ldB(buf, wc * 64 + n * 16 + fr);
    __builtin_amdgcn_s_setprio(1);
#pragma unroll
    for (int m = 0; m < 8; ++m)
#pragma unroll
      for (int n = 0; n < 4; ++n)
        acc[m][n] = __builtin_amdgcn_mfma_f32_16x16x32_bf16(
            a[m], b[n], acc[m][n], 0, 0, 0);
    __builtin_amdgcn_s_setprio(0);
    __syncthreads();   // drains this iter's stage; other block covers stall
  }

  // Epilogue: C/D layout col=fr, row=slot*4+reg [m89/m91]
  float bv[4];
#pragma unroll
  for (int n = 0; n < 4; ++n) bv[n] = bias[bcol + wc * 64 + n * 16 + fr];
#pragma unroll
  for (int m = 0; m < 8; ++m) {
    int grow0 = brow + wr * 128 + m * 16 + slot * 4;
#pragma unroll
    for (int n = 0; n < 4; ++n) {
      int gcol = bcol + wc * 64 + n * 16 + fr;
#pragma unroll
      for (int r = 0; r < 4; ++r)
        C[(size_t)(grow0 + r) * GN + gcol] = acc[m][n][r] + bv[n];
    }
  }
}

// ---------------- Fallback (ws too small): fp32, correct, slow ----------------
__global__ void __launch_bounds__(256) fallback_kernel(
    const float* __restrict__ x, const int* __restrict__ q,
    const float* __restrict__ scale, const float* __restrict__ bias,
    float* __restrict__ out) {
  __shared__ float wrow[GK];
  int n = blockIdx.x;
  for (int k = threadIdx.x; k < GK; k += 256) {
    size_t idx = (size_t)n * GK + k;
    wrow[k] = NF4_LUT[q[idx] & 15] * scale[idx >> 6];
  }
  __syncthreads();
  int m = blockIdx.y * 256 + threadIdx.x;
  const float* xr = x + (size_t)m * GK;
  float acc = 0.f;
  for (int k = 0; k < GK; ++k) acc += xr[k] * wrow[k];
  out[(size_t)m * GN + n] = acc + bias[n];
}

extern "C" void kernel_launch(void* const* d_in, const int* in_sizes, int n_in,
                              void* d_out, int out_size, void* d_ws, size_t ws_size,
                              hipStream_t stream) {
  const float* x = (const float*)d_in[0];
  const int* q = (const int*)d_in[1];
  const float* scale = (const float*)d_in[2];
  const float* bias = (const float*)d_in[3];
  float* out = (float*)d_out;

  const size_t wbytes = (size_t)GN * GK * 2;
  const size_t xbytes = (size_t)GM * GK * 2;

  if (ws_size >= wbytes + xbytes) {
    unsigned short* wq = (unsigned short*)d_ws;
    unsigned short* xb = (unsigned short*)((char*)d_ws + wbytes);
    prep_kernel<<<dim3(8192 + 4096), 256, 0, stream>>>(q, scale, wq, x, xb);
    gemm_cross_kernel<<<dim3((GM / 256) * (GN / 128)), 256, 0, stream>>>(
        xb, wq, bias, out);
  } else {
    fallback_kernel<<<dim3(GN, GM / 256), 256, 0, stream>>>(x, q, scale, bias, out);
  }
}

// Round 13
// 176.103 us; speedup vs baseline: 1.5517x; 1.5517x over previous
//
#include <hip/hip_runtime.h>
#include <stdint.h>

#define GM 4096   // 2*2048 rows of x
#define GN 8192   // out_features
#define GK 2048   // in_features

typedef float f32x4 __attribute__((ext_vector_type(4)));
typedef __bf16 bf16x8 __attribute__((ext_vector_type(8)));

__device__ __constant__ float NF4_LUT[16] = {
    -1.0f, -0.6961928009986877f, -0.5250730514526367f, -0.39491748809814453f,
    -0.28444138169288635f, -0.18477343022823334f, -0.09105003625154495f, 0.0f,
    0.07958029955625534f, 0.16093020141124725f, 0.24611230194568634f,
    0.33791524171829224f, 0.44070982933044434f, 0.5626170039176941f,
    0.7229568362236023f, 1.0f};

__device__ __forceinline__ unsigned short f32_to_bf16_rne(float f) {
  union { float f; uint32_t u; } v;
  v.f = f;
  uint32_t lsb = (v.u >> 16) & 1u;
  v.u += 0x7fffu + lsb;
  return (unsigned short)(v.u >> 16);
}

// ---- Pass 1 (merged): NF4 dequant -> bf16 W  AND  x fp32 -> bf16 ----
__global__ void __launch_bounds__(256) prep_kernel(
    const int* __restrict__ q, const float* __restrict__ scale,
    unsigned short* __restrict__ w, const float* __restrict__ x,
    unsigned short* __restrict__ xb) {
  int b = blockIdx.x;
  if (b < 8192) {
    __shared__ float lut[16];
    if (threadIdx.x < 16) lut[threadIdx.x] = NF4_LUT[threadIdx.x];
    __syncthreads();
    int t = b * 256 + threadIdx.x;
    const int4* q4 = reinterpret_cast<const int4*>(q);
    int4 c0 = q4[2 * t];
    int4 c1 = q4[2 * t + 1];
    float s = scale[t >> 3];
    int codes[8] = {c0.x, c0.y, c0.z, c0.w, c1.x, c1.y, c1.z, c1.w};
    union { unsigned short u[8]; int4 v; } r;
#pragma unroll
    for (int j = 0; j < 8; ++j)
      r.u[j] = f32_to_bf16_rne(lut[codes[j] & 15] * s);
    reinterpret_cast<int4*>(w)[t] = r.v;
  } else {
    int t = (b - 8192) * 256 + threadIdx.x;
    const float4* x4 = reinterpret_cast<const float4*>(x);
    float4 a = x4[2 * t];
    float4 bb = x4[2 * t + 1];
    union { unsigned short u[8]; int4 v; } r;
    r.u[0] = f32_to_bf16_rne(a.x);  r.u[1] = f32_to_bf16_rne(a.y);
    r.u[2] = f32_to_bf16_rne(a.z);  r.u[3] = f32_to_bf16_rne(a.w);
    r.u[4] = f32_to_bf16_rne(bb.x); r.u[5] = f32_to_bf16_rne(bb.y);
    r.u[6] = f32_to_bf16_rne(bb.z); r.u[7] = f32_to_bf16_rne(bb.w);
    reinterpret_cast<int4*>(xb)[t] = r.v;
  }
}

// ------ Pass 2: 256x128 tile, 4 waves, BK=32 dbuf, 2 BLOCKS/CU (fitted) ----
// R12 failed its own mechanism test: 140 arch VGPR + 128 acc = 268 > 256
// -> 1 wave/SIMD -> 1 block/CU (Occupancy 11.5%). Fix: (a) launch_bounds
// (256,2) caps allocation at 256 total/wave (= the budget the 8-wave
// kernels fit); (b) split MFMA into two m-halves so peak live frags drop
// 48 -> 32 arch regs. Target: 2 waves/SIMD from DIFFERENT blocks -> when
// one block drains vmcnt/barrier, the other issues MFMA (m114 overlap).
// Swizzle g ^ ((row>>1)&3): verified 0 conflicts, refcheck'd (R6/R12).
#define AS1(p) ((const __attribute__((address_space(1))) void*)(p))
#define AS3(p) ((__attribute__((address_space(3))) void*)(p))

__global__ void __launch_bounds__(256, 2) gemm_cross_kernel(
    const unsigned short* __restrict__ A,  // [GM][GK] bf16 bits
    const unsigned short* __restrict__ B,  // [GN][GK] bf16 bits
    const float* __restrict__ bias, float* __restrict__ C) {
  constexpr int BK = 32, NT = GK / BK;  // 64 K-tiles
  __shared__ __align__(16) unsigned short As[2 * 256 * 32];  // 32 KB
  __shared__ __align__(16) unsigned short Bs[2 * 128 * 32];  // 16 KB

  int bid = blockIdx.x;                  // nwg = 1024, %8==0 -> bijective
  int swz = (bid & 7) * 128 + (bid >> 3);
  int bm = swz >> 6;                     // 0..15  (A panel, 2 per XCD)
  int bn = swz & 63;                     // 0..63
  int brow = bm * 256, bcol = bn * 128;

  int tid = threadIdx.x;                 // 256 threads = 4 waves
  int lane = tid & 63;
  int wave = tid >> 6;                   // 0..3
  int wr = wave >> 1;                    // 0..1 (M half: 128 rows)
  int wc = wave & 1;                     // 0..1 (N half: 64 cols)
  int fr = lane & 15;
  int slot = lane >> 4;

  const unsigned short* Abase = A + (size_t)brow * GK;
  const unsigned short* Bbase = B + (size_t)bcol * GK;

  f32x4 acc[8][4] = {};

  auto stageA = [&](int buf, int kt) {
#pragma unroll
    for (int i = 0; i < 4; ++i) {
      int c = tid + i * 256;
      int row = c >> 2;
      int gp = (c & 3) ^ ((row >> 1) & 3);
      __builtin_amdgcn_global_load_lds(
          AS1(Abase + (size_t)row * GK + kt + gp * 8),
          AS3((char*)As + buf * 16384 + c * 16), 16, 0, 0);
    }
  };
  auto stageB = [&](int buf, int kt) {
#pragma unroll
    for (int i = 0; i < 2; ++i) {
      int c = tid + i * 256;
      int row = c >> 2;
      int gp = (c & 3) ^ ((row >> 1) & 3);
      __builtin_amdgcn_global_load_lds(
          AS1(Bbase + (size_t)row * GK + kt + gp * 8),
          AS3((char*)Bs + buf * 8192 + c * 16), 16, 0, 0);
    }
  };
  auto ldA = [&](int buf, int row) -> bf16x8 {
    int off = buf * 16384 + row * 64 + ((slot ^ ((row >> 1) & 3)) << 4);
    return *reinterpret_cast<const bf16x8*>((const char*)As + off);
  };
  auto ldB = [&](int buf, int row) -> bf16x8 {
    int off = buf * 8192 + row * 64 + ((slot ^ ((row >> 1) & 3)) << 4);
    return *reinterpret_cast<const bf16x8*>((const char*)Bs + off);
  };

  stageA(0, 0);
  stageB(0, 0);
  __syncthreads();

#pragma unroll 1
  for (int t = 0; t < NT; ++t) {
    int buf = t & 1;
    if (t + 1 < NT) {
      stageA(buf ^ 1, (t + 1) * BK);
      stageB(buf ^ 1, (t + 1) * BK);
    }
    bf16x8 b[4];
#pragma unroll
    for (int n = 0; n < 4; ++n) b[n] = ldB(buf, wc * 64 + n * 16 + fr);
    // m-half 0: load 4 A frags, 16 MFMA (peak live frags = 32 arch regs)
    {
      bf16x8 a[4];
#pragma unroll
      for (int m = 0; m < 4; ++m) a[m] = ldA(buf, wr * 128 + m * 16 + fr);
      __builtin_amdgcn_s_setprio(1);
#pragma unroll
      for (int m = 0; m < 4; ++m)
#pragma unroll
        for (int n = 0; n < 4; ++n)
          acc[m][n] = __builtin_amdgcn_mfma_f32_16x16x32_bf16(
              a[m], b[n], acc[m][n], 0, 0, 0);
      __builtin_amdgcn_s_setprio(0);
    }
    // m-half 1
    {
      bf16x8 a[4];
#pragma unroll
      for (int m = 0; m < 4; ++m)
        a[m] = ldA(buf, wr * 128 + (4 + m) * 16 + fr);
      __builtin_amdgcn_s_setprio(1);
#pragma unroll
      for (int m = 0; m < 4; ++m)
#pragma unroll
        for (int n = 0; n < 4; ++n)
          acc[4 + m][n] = __builtin_amdgcn_mfma_f32_16x16x32_bf16(
              a[m], b[n], acc[4 + m][n], 0, 0, 0);
      __builtin_amdgcn_s_setprio(0);
    }
    __syncthreads();   // full drain; co-resident block covers the stall
  }

  // Epilogue: C/D layout col=fr, row=slot*4+reg [m89/m91]
  float bv[4];
#pragma unroll
  for (int n = 0; n < 4; ++n) bv[n] = bias[bcol + wc * 64 + n * 16 + fr];
#pragma unroll
  for (int m = 0; m < 8; ++m) {
    int grow0 = brow + wr * 128 + m * 16 + slot * 4;
#pragma unroll
    for (int n = 0; n < 4; ++n) {
      int gcol = bcol + wc * 64 + n * 16 + fr;
#pragma unroll
      for (int r = 0; r < 4; ++r)
        C[(size_t)(grow0 + r) * GN + gcol] = acc[m][n][r] + bv[n];
    }
  }
}

// ---------------- Fallback (ws too small): fp32, correct, slow ----------------
__global__ void __launch_bounds__(256) fallback_kernel(
    const float* __restrict__ x, const int* __restrict__ q,
    const float* __restrict__ scale, const float* __restrict__ bias,
    float* __restrict__ out) {
  __shared__ float wrow[GK];
  int n = blockIdx.x;
  for (int k = threadIdx.x; k < GK; k += 256) {
    size_t idx = (size_t)n * GK + k;
    wrow[k] = NF4_LUT[q[idx] & 15] * scale[idx >> 6];
  }
  __syncthreads();
  int m = blockIdx.y * 256 + threadIdx.x;
  const float* xr = x + (size_t)m * GK;
  float acc = 0.f;
  for (int k = 0; k < GK; ++k) acc += xr[k] * wrow[k];
  out[(size_t)m * GN + n] = acc + bias[n];
}

extern "C" void kernel_launch(void* const* d_in, const int* in_sizes, int n_in,
                              void* d_out, int out_size, void* d_ws, size_t ws_size,
                              hipStream_t stream) {
  const float* x = (const float*)d_in[0];
  const int* q = (const int*)d_in[1];
  const float* scale = (const float*)d_in[2];
  const float* bias = (const float*)d_in[3];
  float* out = (float*)d_out;

  const size_t wbytes = (size_t)GN * GK * 2;
  const size_t xbytes = (size_t)GM * GK * 2;

  if (ws_size >= wbytes + xbytes) {
    unsigned short* wq = (unsigned short*)d_ws;
    unsigned short* xb = (unsigned short*)((char*)d_ws + wbytes);
    prep_kernel<<<dim3(8192 + 4096), 256, 0, stream>>>(q, scale, wq, x, xb);
    gemm_cross_kernel<<<dim3((GM / 256) * (GN / 128)), 256, 0, stream>>>(
        xb, wq, bias, out);
  } else {
    fallback_kernel<<<dim3(GN, GM / 256), 256, 0, stream>>>(x, q, scale, bias, out);
  }
}

// Round 14
// 152.542 us; speedup vs baseline: 1.7914x; 1.1545x over previous
//
#include <hip/hip_runtime.h>
#include <stdint.h>

#define GM 4096   // 2*2048 rows of x
#define GN 8192   // out_features
#define GK 2048   // in_features

typedef float f32x4 __attribute__((ext_vector_type(4)));
typedef __bf16 bf16x8 __attribute__((ext_vector_type(8)));

__device__ __constant__ float NF4_LUT[16] = {
    -1.0f, -0.6961928009986877f, -0.5250730514526367f, -0.39491748809814453f,
    -0.28444138169288635f, -0.18477343022823334f, -0.09105003625154495f, 0.0f,
    0.07958029955625534f, 0.16093020141124725f, 0.24611230194568634f,
    0.33791524171829224f, 0.44070982933044434f, 0.5626170039176941f,
    0.7229568362236023f, 1.0f};

__device__ __forceinline__ unsigned short f32_to_bf16_rne(float f) {
  union { float f; uint32_t u; } v;
  v.f = f;
  uint32_t lsb = (v.u >> 16) & 1u;
  v.u += 0x7fffu + lsb;
  return (unsigned short)(v.u >> 16);
}

// ---- Pass 1 (merged): NF4 dequant -> bf16 W  AND  x fp32 -> bf16 ----
// W: GN*GK/8 threads = 8192 blocks. x: GM*GK/8 threads = 4096 blocks.
__global__ void __launch_bounds__(256) prep_kernel(
    const int* __restrict__ q, const float* __restrict__ scale,
    unsigned short* __restrict__ w, const float* __restrict__ x,
    unsigned short* __restrict__ xb) {
  int b = blockIdx.x;
  if (b < 8192) {
    __shared__ float lut[16];
    if (threadIdx.x < 16) lut[threadIdx.x] = NF4_LUT[threadIdx.x];
    __syncthreads();
    int t = b * 256 + threadIdx.x;
    const int4* q4 = reinterpret_cast<const int4*>(q);
    int4 c0 = q4[2 * t];
    int4 c1 = q4[2 * t + 1];
    float s = scale[t >> 3];
    int codes[8] = {c0.x, c0.y, c0.z, c0.w, c1.x, c1.y, c1.z, c1.w};
    union { unsigned short u[8]; int4 v; } r;
#pragma unroll
    for (int j = 0; j < 8; ++j)
      r.u[j] = f32_to_bf16_rne(lut[codes[j] & 15] * s);
    reinterpret_cast<int4*>(w)[t] = r.v;
  } else {
    int t = (b - 8192) * 256 + threadIdx.x;
    const float4* x4 = reinterpret_cast<const float4*>(x);
    float4 a = x4[2 * t];
    float4 bb = x4[2 * t + 1];
    union { unsigned short u[8]; int4 v; } r;
    r.u[0] = f32_to_bf16_rne(a.x);  r.u[1] = f32_to_bf16_rne(a.y);
    r.u[2] = f32_to_bf16_rne(a.z);  r.u[3] = f32_to_bf16_rne(a.w);
    r.u[4] = f32_to_bf16_rne(bb.x); r.u[5] = f32_to_bf16_rne(bb.y);
    r.u[6] = f32_to_bf16_rne(bb.z); r.u[7] = f32_to_bf16_rne(bb.w);
    reinterpret_cast<int4*>(xb)[t] = r.v;
  }
}

// ------ Pass 2: persistent 256x256 GEMM (best-measured variant) ------
// 8 waves (2Mx4N), BK=64, 16x16x32 MFMA, LDS 2x64KB static parity bufs.
// Snake quadrants with read-ahead groups; stages P1:B1(O), P3:A0+B0(E+2),
// P4:A1(E+2), P5:B1(E+2), P7:A0+B0(O+2), P8:A1(O+2); vmcnt(6) at P4/P8.
// T2 swizzle byte ^= ((row&7)<<4) via pre-swizzled global src (0 conflicts).
// Persistent: 2 output tiles/block, XCD-affine B pair-panels (FETCH ~156MB),
// tile-1 flush drains under tile-2's K-loop.
// Converged plateau: 134.5us, MfmaUtil 45%, ~1020 TF (see R13 post-mortem).
#define AS1(p) ((const __attribute__((address_space(1))) void*)(p))
#define AS3(p) ((__attribute__((address_space(3))) void*)(p))
#define VM6() asm volatile("s_waitcnt vmcnt(6)" ::: "memory")
#define FENCE() asm volatile("" ::: "memory")
#define BAR() do { FENCE(); __builtin_amdgcn_s_barrier(); FENCE(); } while (0)

__global__ void __launch_bounds__(512, 1) gemm_8phase_kernel(
    const unsigned short* __restrict__ A,  // [GM][GK] bf16 bits
    const unsigned short* __restrict__ B,  // [GN][GK] bf16 bits
    const float* __restrict__ bias, float* __restrict__ C) {
  constexpr int BK = 64;
  constexpr int NV = 64;  // virtual K-tiles: 2 output tiles x 32
  __shared__ __align__(16) unsigned short As[2 * 256 * 64];  // 64 KB
  __shared__ __align__(16) unsigned short Bs[2 * 256 * 64];  // 64 KB

  int bid = blockIdx.x;                    // nwg = 256, %8==0 -> bijective
  int swz = (bid & 7) * 32 + (bid >> 3);
  int brow = (swz & 15) * 256;             // A panel varies within XCD
  int pair = swz >> 4;                     // B pair-panel is XCD-affine
  int bcol0 = pair * 512;

  int tid = threadIdx.x;
  int lane = tid & 63;
  int wave = tid >> 6;
  int wr = wave >> 2;   // 0..1
  int wc = wave & 3;    // 0..3
  int fr = lane & 15;
  int slot = lane >> 4;
  int swc = (slot << 4) ^ ((fr & 7) << 4);

  const unsigned short* Abase = A + (size_t)brow * GK;
  const unsigned short* Bbase0 = B + (size_t)bcol0 * GK;
  const unsigned short* Bbase1 = Bbase0 + (size_t)256 * GK;

  int arow = (wr * 64 + fr) * 128;
  int brw = (wc * 32 + fr) * 128;

  f32x4 acc[8][4] = {};
  bf16x8 a0[2][4][2], a1[2][4][2], b0[2][2][2], b1[2][2][2];

  auto ldA = [&](int buf, int qm, int m, int kk) -> bf16x8 {
    int off = buf * 32768 + qm * 16384 + m * 2048 + arow + (swc ^ (kk << 6));
    return *reinterpret_cast<const bf16x8*>((const char*)As + off);
  };
  auto ldB = [&](int buf, int qn, int n, int kk) -> bf16x8 {
    int off = buf * 32768 + qn * 16384 + n * 2048 + brw + (swc ^ (kk << 6));
    return *reinterpret_cast<const bf16x8*>((const char*)Bs + off);
  };
  auto stage = [&](const unsigned short* gtile, unsigned short* lds, int buf,
                   int h, int kt) {
#pragma unroll
    for (int i = 0; i < 2; ++i) {
      int L = h * 16384 + i * 8192 + tid * 16;
      int s = L ^ (((L >> 7) & 7) << 4);
      __builtin_amdgcn_global_load_lds(
          AS1(gtile + (size_t)(s >> 7) * GK + kt + ((s & 127) >> 1)),
          AS3((char*)lds + buf * 32768 + L), 16, 0, 0);
    }
  };
  auto RD_A1 = [&](int p) {
#pragma unroll
    for (int m = 0; m < 4; ++m)
#pragma unroll
      for (int kk = 0; kk < 2; ++kk) a1[p][m][kk] = ldA(p, 1, m, kk);
  };
  auto RD_B1 = [&](int p) {
#pragma unroll
    for (int n = 0; n < 2; ++n)
#pragma unroll
      for (int kk = 0; kk < 2; ++kk) b1[p][n][kk] = ldB(p, 1, n, kk);
  };
  auto RD_A0B0 = [&](int p) {
#pragma unroll
    for (int m = 0; m < 4; ++m)
#pragma unroll
      for (int kk = 0; kk < 2; ++kk) a0[p][m][kk] = ldA(p, 0, m, kk);
#pragma unroll
    for (int n = 0; n < 2; ++n)
#pragma unroll
      for (int kk = 0; kk < 2; ++kk) b0[p][n][kk] = ldB(p, 0, n, kk);
  };
  auto Q1 = [&](int p) {
    __builtin_amdgcn_s_setprio(1);
#pragma unroll
    for (int m = 0; m < 4; ++m)
#pragma unroll
      for (int n = 0; n < 2; ++n)
#pragma unroll
        for (int kk = 0; kk < 2; ++kk)
          acc[m][n] = __builtin_amdgcn_mfma_f32_16x16x32_bf16(
              a0[p][m][kk], b0[p][n][kk], acc[m][n], 0, 0, 0);
    __builtin_amdgcn_s_setprio(0);
  };
  auto Q2 = [&](int p) {
    __builtin_amdgcn_s_setprio(1);
#pragma unroll
    for (int m = 0; m < 4; ++m)
#pragma unroll
      for (int n = 0; n < 2; ++n)
#pragma unroll
        for (int kk = 0; kk < 2; ++kk)
          acc[4 + m][n] = __builtin_amdgcn_mfma_f32_16x16x32_bf16(
              a1[p][m][kk], b0[p][n][kk], acc[4 + m][n], 0, 0, 0);
    __builtin_amdgcn_s_setprio(0);
  };
  auto Q3 = [&](int p) {
    __builtin_amdgcn_s_setprio(1);
#pragma unroll
    for (int m = 0; m < 4; ++m)
#pragma unroll
      for (int n = 0; n < 2; ++n)
#pragma unroll
        for (int kk = 0; kk < 2; ++kk)
          acc[4 + m][2 + n] = __builtin_amdgcn_mfma_f32_16x16x32_bf16(
              a1[p][m][kk], b1[p][n][kk], acc[4 + m][2 + n], 0, 0, 0);
    __builtin_amdgcn_s_setprio(0);
  };
  auto Q4 = [&](int p) {
    __builtin_amdgcn_s_setprio(1);
#pragma unroll
    for (int m = 0; m < 4; ++m)
#pragma unroll
      for (int n = 0; n < 2; ++n)
#pragma unroll
        for (int kk = 0; kk < 2; ++kk)
          acc[m][2 + n] = __builtin_amdgcn_mfma_f32_16x16x32_bf16(
              a0[p][m][kk], b1[p][n][kk], acc[m][2 + n], 0, 0, 0);
    __builtin_amdgcn_s_setprio(0);
  };
  auto flush = [&](int bc) {
    float bv[4];
#pragma unroll
    for (int n = 0; n < 4; ++n)
      bv[n] = bias[bc + (n >> 1) * 128 + wc * 32 + (n & 1) * 16 + fr];
#pragma unroll
    for (int m = 0; m < 8; ++m) {
      int grow0 = brow + (m >> 2) * 128 + wr * 64 + (m & 3) * 16 + slot * 4;
#pragma unroll
      for (int n = 0; n < 4; ++n) {
        int gcol = bc + (n >> 1) * 128 + wc * 32 + (n & 1) * 16 + fr;
#pragma unroll
        for (int r = 0; r < 4; ++r)
          C[(size_t)(grow0 + r) * GN + gcol] = acc[m][n][r] + bv[n];
      }
    }
  };
  auto iter = [&](int j) {
    int t1 = 2 * j + 1;
    int t2 = 2 * j + 2; if (t2 > NV - 1) t2 = NV - 1;  // tail dummy restage
    int t3 = 2 * j + 3; if (t3 > NV - 1) t3 = NV - 1;
    const unsigned short* B1p = (t1 < 32) ? Bbase0 : Bbase1;
    const unsigned short* B2p = (t2 < 32) ? Bbase0 : Bbase1;
    const unsigned short* B3p = (t3 < 32) ? Bbase0 : Bbase1;
    int kt1 = (t1 & 31) * BK, kt2 = (t2 & 31) * BK, kt3 = (t3 & 31) * BK;
    // P1
    RD_A1(0);
    stage(B1p, Bs, 1, 1, kt1);
    BAR();
    Q1(0);
    // P2
    RD_B1(0);
    BAR();
    Q2(0);
    // P3
    stage(Abase, As, 0, 0, kt2);
    stage(B2p, Bs, 0, 0, kt2);
    BAR();
    Q3(0);
    // P4
    stage(Abase, As, 0, 1, kt2);
    VM6();
    BAR();
    RD_A0B0(1);
    Q4(0);
    // P5
    RD_A1(1);
    stage(B2p, Bs, 0, 1, kt2);
    BAR();
    Q1(1);
    // P6
    RD_B1(1);
    BAR();
    Q2(1);
    // P7
    stage(Abase, As, 1, 0, kt3);
    stage(B3p, Bs, 1, 0, kt3);
    BAR();
    Q3(1);
    // P8
    stage(Abase, As, 1, 1, kt3);
    VM6();
    BAR();
    RD_A0B0(0);
    Q4(1);
  };

  // Prologue: stage v0 fully + v1 {A0,B0,A1}
  stage(Abase, As, 0, 0, 0);
  stage(Bbase0, Bs, 0, 0, 0);
  stage(Abase, As, 0, 1, 0);
  stage(Bbase0, Bs, 0, 1, 0);
  stage(Abase, As, 1, 0, BK);
  stage(Bbase0, Bs, 1, 0, BK);
  stage(Abase, As, 1, 1, BK);
  VM6();
  BAR();
  RD_A0B0(0);

#pragma unroll 1
  for (int j = 0; j < 16; ++j) iter(j);

  // mid-flush: tile-1 stores fly while tile-2's K-loop runs
  flush(bcol0);
#pragma unroll
  for (int m = 0; m < 8; ++m)
#pragma unroll
    for (int n = 0; n < 4; ++n)
      acc[m][n] = f32x4{0.f, 0.f, 0.f, 0.f};

#pragma unroll 1
  for (int j = 16; j < 32; ++j) iter(j);

  flush(bcol0 + 256);
}

// ---------------- Fallback (ws too small): fp32, correct, slow ----------------
__global__ void __launch_bounds__(256) fallback_kernel(
    const float* __restrict__ x, const int* __restrict__ q,
    const float* __restrict__ scale, const float* __restrict__ bias,
    float* __restrict__ out) {
  __shared__ float wrow[GK];
  int n = blockIdx.x;
  for (int k = threadIdx.x; k < GK; k += 256) {
    size_t idx = (size_t)n * GK + k;
    wrow[k] = NF4_LUT[q[idx] & 15] * scale[idx >> 6];
  }
  __syncthreads();
  int m = blockIdx.y * 256 + threadIdx.x;
  const float* xr = x + (size_t)m * GK;
  float acc = 0.f;
  for (int k = 0; k < GK; ++k) acc += xr[k] * wrow[k];
  out[(size_t)m * GN + n] = acc + bias[n];
}

extern "C" void kernel_launch(void* const* d_in, const int* in_sizes, int n_in,
                              void* d_out, int out_size, void* d_ws, size_t ws_size,
                              hipStream_t stream) {
  const float* x = (const float*)d_in[0];
  const int* q = (const int*)d_in[1];
  const float* scale = (const float*)d_in[2];
  const float* bias = (const float*)d_in[3];
  float* out = (float*)d_out;

  const size_t wbytes = (size_t)GN * GK * 2;
  const size_t xbytes = (size_t)GM * GK * 2;

  if (ws_size >= wbytes + xbytes) {
    unsigned short* wq = (unsigned short*)d_ws;
    unsigned short* xb = (unsigned short*)((char*)d_ws + wbytes);
    prep_kernel<<<dim3(8192 + 4096), 256, 0, stream>>>(q, scale, wq, x, xb);
    gemm_8phase_kernel<<<dim3(256), 512, 0, stream>>>(xb, wq, bias, out);
  } else {
    fallback_kernel<<<dim3(GN, GM / 256), 256, 0, stream>>>(x, q, scale, bias, out);
  }
}